// Round 1
// baseline (116.159 us; speedup 1.0000x reference)
//
#include <hip/hip_runtime.h>
#include <hip/hip_bf16.h>

typedef float f32x4 __attribute__((ext_vector_type(4)));
typedef short s16x8 __attribute__((ext_vector_type(8)));

#define LOG2_N 2.887525271f   // log2(7.4)
#define HALF_N 3.7f           // n_param / 2

// ---------------- kernel 1: A[m,k] = 3.7 * clip(x,0,1)^log2(7.4)  (bf16) ----
__global__ __launch_bounds__(256) void fv_kernel(const float* __restrict__ x,
                                                 __hip_bfloat16* __restrict__ a,
                                                 int total4) {
  int i = blockIdx.x * blockDim.x + threadIdx.x;
  if (i >= total4) return;
  float4 v = reinterpret_cast<const float4*>(x)[i];
  const float* vp = reinterpret_cast<const float*>(&v);
  union { ushort4 u4; ushort s[4]; } o;
#pragma unroll
  for (int j = 0; j < 4; ++j) {
    float xc = fminf(fmaxf(vp[j], 0.0f), 1.0f);
    float r = (xc > 0.0f) ? HALF_N * exp2f(LOG2_N * __log2f(xc)) : 0.0f;
    __hip_bfloat16 h = __float2bfloat16(r);
    o.s[j] = *reinterpret_cast<ushort*>(&h);
  }
  reinterpret_cast<ushort4*>(a)[i] = o.u4;
}

// ---------------- kernel 2: WT[n][k] = bf16(w[k][n]) ------------------------
__global__ __launch_bounds__(256) void wt_kernel(const float* __restrict__ w,
                                                 __hip_bfloat16* __restrict__ wt,
                                                 int K, int N) {
  __shared__ float tile[64][65];
  const int n0 = blockIdx.x * 64;
  const int k0 = blockIdx.y * 64;
  const int tid = threadIdx.x;
#pragma unroll
  for (int i = 0; i < 16; ++i) {
    const int lin = i * 256 + tid;
    const int r = lin >> 6;   // 0..63 (k within tile)
    const int c = lin & 63;   // 0..63 (n within tile)
    tile[r][c] = w[(size_t)(k0 + r) * N + (n0 + c)];
  }
  __syncthreads();
  const int kk = (tid & 31) * 2;  // 0..62, even
  const int r0 = tid >> 5;        // 0..7
#pragma unroll
  for (int i = 0; i < 8; ++i) {
    const int r = r0 + i * 8;     // n within tile
    __hip_bfloat16 h0 = __float2bfloat16(tile[kk][r]);
    __hip_bfloat16 h1 = __float2bfloat16(tile[kk + 1][r]);
    ushort2 u;
    u.x = *reinterpret_cast<ushort*>(&h0);
    u.y = *reinterpret_cast<ushort*>(&h1);
    *reinterpret_cast<ushort2*>(&wt[(size_t)(n0 + r) * K + (k0 + kk)]) = u;
  }
}

// ---------------- kernel 3: C = A @ WT^T + 3.7*b  (m97-structure GEMM) ------
#define BM 128
#define BN 128
#define BK 32

#define GLD16(g, l)                                              \
  __builtin_amdgcn_global_load_lds(                              \
      (const __attribute__((address_space(1))) void*)(g),        \
      (__attribute__((address_space(3))) void*)(l), 16, 0, 0)

__global__ __launch_bounds__(256) void gemm_kernel(
    const __hip_bfloat16* __restrict__ A,   // [M][K] bf16
    const __hip_bfloat16* __restrict__ BT,  // [N][K] bf16
    const float* __restrict__ bias,         // [N]
    float* __restrict__ C,                  // [M][N]
    int M, int N, int K) {
  __shared__ ushort Als[2][BM][BK];   // 8 KB per buf
  __shared__ ushort Bls[2][BN][BK];

  const int ntn = N / BN;
  const int m0 = (blockIdx.x / ntn) * BM;
  const int n0 = (blockIdx.x % ntn) * BN;

  const int tid = threadIdx.x;
  const int lane = tid & 63;
  const int wid = tid >> 6;
  const int wr = wid >> 1;  // 0..1
  const int wc = wid & 1;   // 0..1

  // staging: linear byte off within tile = tid*16 (+4096 for 2nd issue)
  const int srow = tid >> 2;        // 0..63
  const int scol = (tid & 3) * 8;   // ushort offset in row
  const size_t aBase = (size_t)(m0 + srow) * K + scol;
  const size_t bBase = (size_t)(n0 + srow) * K + scol;
  const int ldsW = wid * 512;       // ushort offset of wave chunk (1 KB/wave)

  const ushort* Au = (const ushort*)A;
  const ushort* Bu = (const ushort*)BT;

  f32x4 acc[4][4];
#pragma unroll
  for (int i = 0; i < 4; ++i)
#pragma unroll
    for (int j = 0; j < 4; ++j)
#pragma unroll
      for (int r = 0; r < 4; ++r) acc[i][j][r] = 0.0f;

  auto stage = [&](int buf, int t) {
    const ushort* ag = Au + aBase + (size_t)t * BK;
    const ushort* bg = Bu + bBase + (size_t)t * BK;
    GLD16(ag,             &Als[buf][0][0] + ldsW);
    GLD16(ag + 64 * (size_t)K, &Als[buf][0][0] + 2048 + ldsW);
    GLD16(bg,             &Bls[buf][0][0] + ldsW);
    GLD16(bg + 64 * (size_t)K, &Bls[buf][0][0] + 2048 + ldsW);
  };

  const int frow = lane & 15;
  const int fcol = (lane >> 4) * 8;  // ushort offset (8 contiguous k per lane)

  stage(0, 0);
  __syncthreads();   // drains vmcnt before barrier (compiler-emitted)

  const int NT = K / BK;
  for (int t = 0; t < NT; ++t) {
    const int cur = t & 1;
    if (t + 1 < NT) stage(cur ^ 1, t + 1);
    s16x8 af[4], bf[4];
#pragma unroll
    for (int mi = 0; mi < 4; ++mi)
      af[mi] = *(const s16x8*)&Als[cur][wr * 64 + mi * 16 + frow][fcol];
#pragma unroll
    for (int ni = 0; ni < 4; ++ni)
      bf[ni] = *(const s16x8*)&Bls[cur][wc * 64 + ni * 16 + frow][fcol];
#pragma unroll
    for (int mi = 0; mi < 4; ++mi)
#pragma unroll
      for (int ni = 0; ni < 4; ++ni)
        acc[mi][ni] = __builtin_amdgcn_mfma_f32_16x16x32_bf16(
            af[mi], bf[ni], acc[mi][ni], 0, 0, 0);
    __syncthreads();
  }

  // epilogue: C/D layout col = lane&15, row = (lane>>4)*4 + reg
  const int ccol = lane & 15;
  const int crow = (lane >> 4) * 4;
#pragma unroll
  for (int ni = 0; ni < 4; ++ni) {
    const int gc = n0 + wc * 64 + ni * 16 + ccol;
    const float bv = HALF_N * bias[gc];
#pragma unroll
    for (int mi = 0; mi < 4; ++mi) {
      const int gr = m0 + wr * 64 + mi * 16 + crow;
#pragma unroll
      for (int r = 0; r < 4; ++r)
        C[(size_t)(gr + r) * N + gc] = acc[mi][ni][r] + bv;
    }
  }
}

extern "C" void kernel_launch(void* const* d_in, const int* in_sizes, int n_in,
                              void* d_out, int out_size, void* d_ws, size_t ws_size,
                              hipStream_t stream) {
  const float* x = (const float*)d_in[0];
  const float* w = (const float*)d_in[1];
  const float* b = (const float*)d_in[2];
  float* y = (float*)d_out;

  const int N = in_sizes[2];             // 4096
  const int K = in_sizes[1] / N;         // 4096
  const int M = in_sizes[0] / K;         // 2048

  __hip_bfloat16* Abf = (__hip_bfloat16*)d_ws;
  __hip_bfloat16* WT  = (__hip_bfloat16*)((char*)d_ws + (size_t)M * K * 2);
  if (ws_size < (size_t)M * K * 2 + (size_t)N * K * 2) return;  // need 48 MB

  // 1) A = 3.7 * clip(x)^log2(7.4) in bf16
  const int total4 = (M * K) / 4;
  fv_kernel<<<(total4 + 255) / 256, 256, 0, stream>>>(x, Abf, total4);

  // 2) WT = transpose(w) in bf16
  wt_kernel<<<dim3(N / 64, K / 64), dim3(256), 0, stream>>>(w, WT, K, N);

  // 3) y = A @ w + 3.7*b
  const int grid = (M / BM) * (N / BN);
  gemm_kernel<<<grid, 256, 0, stream>>>(Abf, WT, b, y, M, N, K);
}

// Round 2
// 115.465 us; speedup vs baseline: 1.0060x; 1.0060x over previous
//
#include <hip/hip_runtime.h>
#include <hip/hip_bf16.h>

typedef float f32x4 __attribute__((ext_vector_type(4)));
typedef short s16x8 __attribute__((ext_vector_type(8)));

#define LOG2_N 2.887525271f   // log2(7.4)
#define HALF_N 3.7f           // n_param / 2

// ---------------- kernel 1: A[m,k] = 3.7 * clip(x,0,1)^log2(7.4)  (bf16) ----
__global__ __launch_bounds__(256) void fv_kernel(const float* __restrict__ x,
                                                 __hip_bfloat16* __restrict__ a,
                                                 int total4) {
  int i = blockIdx.x * blockDim.x + threadIdx.x;
  if (i >= total4) return;
  float4 v = reinterpret_cast<const float4*>(x)[i];
  const float* vp = reinterpret_cast<const float*>(&v);
  union { ushort4 u4; ushort s[4]; } o;
#pragma unroll
  for (int j = 0; j < 4; ++j) {
    float xc = fminf(fmaxf(vp[j], 0.0f), 1.0f);
    float r = (xc > 0.0f) ? HALF_N * exp2f(LOG2_N * __log2f(xc)) : 0.0f;
    __hip_bfloat16 h = __float2bfloat16(r);
    o.s[j] = *reinterpret_cast<ushort*>(&h);
  }
  reinterpret_cast<ushort4*>(a)[i] = o.u4;
}

// ---------------- kernel 2: WT[n][k] = bf16(w[k][n]) ------------------------
__global__ __launch_bounds__(256) void wt_kernel(const float* __restrict__ w,
                                                 __hip_bfloat16* __restrict__ wt,
                                                 int K, int N) {
  __shared__ float tile[64][65];
  const int n0 = blockIdx.x * 64;
  const int k0 = blockIdx.y * 64;
  const int tid = threadIdx.x;
#pragma unroll
  for (int i = 0; i < 16; ++i) {
    const int lin = i * 256 + tid;
    const int r = lin >> 6;   // k within tile
    const int c = lin & 63;   // n within tile
    tile[r][c] = w[(size_t)(k0 + r) * N + (n0 + c)];
  }
  __syncthreads();
  const int kk = (tid & 31) * 2;  // 0..62, even
  const int r0 = tid >> 5;        // 0..7
#pragma unroll
  for (int i = 0; i < 8; ++i) {
    const int r = r0 + i * 8;     // n within tile
    __hip_bfloat16 h0 = __float2bfloat16(tile[kk][r]);
    __hip_bfloat16 h1 = __float2bfloat16(tile[kk + 1][r]);
    ushort2 u;
    u.x = *reinterpret_cast<ushort*>(&h0);
    u.y = *reinterpret_cast<ushort*>(&h1);
    *reinterpret_cast<ushort2*>(&wt[(size_t)(n0 + r) * K + (k0 + kk)]) = u;
  }
}

// ---------------- kernel 3: 8-wave 128x256 4-phase GEMM (T2+T3+T4+T5) -------
#define BM 128
#define BN 256
#define BK 64
// LDS buffer (ushort units): A [128][64] at 0 (8192), B [256][64] at 8192.
#define LDS_HALF 24576   // ushorts per buffer (48 KB)
#define B_OFF 8192

#define GLD16(g, l)                                              \
  __builtin_amdgcn_global_load_lds(                              \
      (const __attribute__((address_space(1))) void*)(g),        \
      (__attribute__((address_space(3))) void*)(l), 16, 0, 0)

__global__ __launch_bounds__(512, 2) void gemm_kernel(
    const __hip_bfloat16* __restrict__ A,   // [M][K] bf16
    const __hip_bfloat16* __restrict__ BT,  // [N][K] bf16
    const float* __restrict__ bias,         // [N]
    float* __restrict__ C,                  // [M][N]
    int M, int N, int K) {
  __shared__ ushort lds[2][LDS_HALF];   // 96 KB

  const int NTM = M / BM;               // 16
  const int NTN = N / BN;               // 16
  const int nwg = NTM * NTN;

  // XCD-aware bijective swizzle (nwg % 8 == 0 here)
  int wg = (int)blockIdx.x;
  if ((nwg & 7) == 0) wg = (wg & 7) * (nwg >> 3) + (wg >> 3);
  const int nt = wg / NTM;              // B-panel resident per XCD
  const int mt = wg % NTM;
  const int m0 = mt * BM;
  const int n0 = nt * BN;

  const int tid = threadIdx.x;
  const int lane = tid & 63;
  const int wid = tid >> 6;   // 0..7
  const int wr = wid >> 2;    // 0..1  (M half)
  const int wc = wid & 3;     // 0..3  (N quarter)

  const ushort* Au = (const ushort*)A;
  const ushort* Bu = (const ushort*)BT;

  // ---- staging precompute (T2: pre-swizzled global source, linear LDS dest)
  // per gld_lds: LDS byte loc = chunkbase + lane*16; row = loc>>7,
  // c16 = (loc>>4)&7; source column block c16' = c16 ^ (row&7).
  const int l8 = lane >> 3;                  // == row&7 for every chunk
  const int c16s = (lane & 7) ^ l8;          // swizzled source col16
  const int rA0 = wid * 16 + l8;             // A rows, instr 0
  const int rA1 = rA0 + 8;                   //         instr 1
  const int rB0 = wid * 32 + l8;             // B rows, instrs 0..3
  const ushort* aSrc0 = Au + (size_t)(m0 + rA0) * K + c16s * 8;
  const ushort* aSrc1 = Au + (size_t)(m0 + rA1) * K + c16s * 8;
  const ushort* bSrc0 = Bu + (size_t)(n0 + rB0) * K + c16s * 8;
  const ushort* bSrc1 = bSrc0 + (size_t)8 * K;
  const ushort* bSrc2 = bSrc0 + (size_t)16 * K;
  const ushort* bSrc3 = bSrc0 + (size_t)24 * K;
  const int aDst0 = wid * 1024;
  const int aDst1 = wid * 1024 + 512;
  const int bDst0 = B_OFF + wid * 2048;

  // ---- fragment read addressing (swizzled ds_read)
  const int frow = lane & 15;
  const int lhi = lane >> 4;                 // 0..3
  const int f7 = frow & 7;
  const int sc0 = lhi ^ f7;                  // kk=0 swizzled col16
  const int sc1 = sc0 ^ 4;                   // kk=1
  const int aRow = (wr * 64 + frow) * 64;    // ushort base into A region
  const int bRow = B_OFF + (wc * 64 + frow) * 64;

  f32x4 acc[4][4];
#pragma unroll
  for (int i = 0; i < 4; ++i)
#pragma unroll
    for (int j = 0; j < 4; ++j)
#pragma unroll
      for (int r = 0; r < 4; ++r) acc[i][j][r] = 0.0f;

  auto stagePart = [&](int buf, int t, int p) {
    const int to = t * BK;  // ushort offset per K-tile
    if (p == 0) {
      GLD16(aSrc0 + to, &lds[buf][aDst0]);
      GLD16(aSrc1 + to, &lds[buf][aDst1]);
    } else if (p == 1) {
      GLD16(bSrc0 + to, &lds[buf][bDst0]);
      GLD16(bSrc1 + to, &lds[buf][bDst0 + 512]);
    } else if (p == 2) {
      GLD16(bSrc2 + to, &lds[buf][bDst0 + 1024]);
    } else {
      GLD16(bSrc3 + to, &lds[buf][bDst0 + 1536]);
    }
  };

  // prologue: stage tile 0, drain, sync
  stagePart(0, 0, 0);
  stagePart(0, 0, 1);
  stagePart(0, 0, 2);
  stagePart(0, 0, 3);
  asm volatile("s_waitcnt vmcnt(0)" ::: "memory");
  __builtin_amdgcn_s_barrier();

  const int NT = K / BK;
  for (int t = 0; t < NT; ++t) {
    const int cur = t & 1;
    const bool pf = (t + 1 < NT);
#pragma unroll
    for (int ph = 0; ph < 4; ++ph) {
      const int qm = ph >> 1;     // C-quadrant of this wave's 64x64 output
      const int qn = ph & 1;
      // 8 ds_read_b128 (swizzled addresses; compiler inserts lgkmcnt)
      s16x8 a[2][2], b[2][2];
#pragma unroll
      for (int u = 0; u < 2; ++u) {
        const int ar = aRow + (qm * 2 + u) * 1024;
        a[u][0] = *(const s16x8*)&lds[cur][ar + sc0 * 8];
        a[u][1] = *(const s16x8*)&lds[cur][ar + sc1 * 8];
      }
#pragma unroll
      for (int v = 0; v < 2; ++v) {
        const int br = bRow + (qn * 2 + v) * 1024;
        b[v][0] = *(const s16x8*)&lds[cur][br + sc0 * 8];
        b[v][1] = *(const s16x8*)&lds[cur][br + sc1 * 8];
      }
      // prefetch next tile (loads stay in flight across barriers - T4)
      if (pf) stagePart(cur ^ 1, t + 1, ph);
      __builtin_amdgcn_s_barrier();
      __builtin_amdgcn_s_setprio(1);
#pragma unroll
      for (int u = 0; u < 2; ++u)
#pragma unroll
        for (int v = 0; v < 2; ++v) {
          f32x4* ac = &acc[qm * 2 + u][qn * 2 + v];
          *ac = __builtin_amdgcn_mfma_f32_16x16x32_bf16(a[u][0], b[v][0], *ac, 0, 0, 0);
          *ac = __builtin_amdgcn_mfma_f32_16x16x32_bf16(a[u][1], b[v][1], *ac, 0, 0, 0);
        }
      __builtin_amdgcn_s_setprio(0);
      if (ph == 3) asm volatile("s_waitcnt vmcnt(0)" ::: "memory");
      __builtin_amdgcn_s_barrier();
    }
  }

  // epilogue: C/D layout col = lane&15, row = (lane>>4)*4 + reg
  const int ccol = lane & 15;
  const int crow = (lane >> 4) * 4;
#pragma unroll
  for (int ni = 0; ni < 4; ++ni) {
    const int gc = n0 + wc * 64 + ni * 16 + ccol;
    const float bv = HALF_N * bias[gc];
#pragma unroll
    for (int mi = 0; mi < 4; ++mi) {
      const int gr = m0 + wr * 64 + mi * 16 + crow;
#pragma unroll
      for (int r = 0; r < 4; ++r)
        C[(size_t)(gr + r) * N + gc] = acc[mi][ni][r] + bv;
    }
  }
}

extern "C" void kernel_launch(void* const* d_in, const int* in_sizes, int n_in,
                              void* d_out, int out_size, void* d_ws, size_t ws_size,
                              hipStream_t stream) {
  const float* x = (const float*)d_in[0];
  const float* w = (const float*)d_in[1];
  const float* b = (const float*)d_in[2];
  float* y = (float*)d_out;

  const int N = in_sizes[2];             // 4096
  const int K = in_sizes[1] / N;         // 4096
  const int M = in_sizes[0] / K;         // 2048

  __hip_bfloat16* Abf = (__hip_bfloat16*)d_ws;
  __hip_bfloat16* WT  = (__hip_bfloat16*)((char*)d_ws + (size_t)M * K * 2);
  if (ws_size < (size_t)M * K * 2 + (size_t)N * K * 2) return;  // need 48 MB

  // 1) A = 3.7 * clip(x)^log2(7.4) in bf16
  const int total4 = (M * K) / 4;
  fv_kernel<<<(total4 + 255) / 256, 256, 0, stream>>>(x, Abf, total4);

  // 2) WT = transpose(w) in bf16
  wt_kernel<<<dim3(N / 64, K / 64), dim3(256), 0, stream>>>(w, WT, K, N);

  // 3) y = A @ w + 3.7*b
  const int grid = (M / BM) * (N / BN);
  gemm_kernel<<<grid, 512, 0, stream>>>(Abf, WT, b, y, M, N, K);
}

// Round 3
// 98.882 us; speedup vs baseline: 1.1747x; 1.1677x over previous
//
#include <hip/hip_runtime.h>
#include <hip/hip_bf16.h>

typedef float f32x4 __attribute__((ext_vector_type(4)));
typedef short s16x8 __attribute__((ext_vector_type(8)));

#define LOG2_N 2.887525271f   // log2(7.4)
#define HALF_N 3.7f           // n_param / 2

// ---------------- kernel 1: A[m,k] = 3.7 * clip(x,0,1)^log2(7.4)  (bf16) ----
__global__ __launch_bounds__(256) void fv_kernel(const float* __restrict__ x,
                                                 __hip_bfloat16* __restrict__ a,
                                                 int total4) {
  int i = blockIdx.x * blockDim.x + threadIdx.x;
  if (i >= total4) return;
  float4 v = reinterpret_cast<const float4*>(x)[i];
  const float* vp = reinterpret_cast<const float*>(&v);
  union { ushort4 u4; ushort s[4]; } o;
#pragma unroll
  for (int j = 0; j < 4; ++j) {
    float xc = fminf(fmaxf(vp[j], 0.0f), 1.0f);
    float r = (xc > 0.0f) ? HALF_N * exp2f(LOG2_N * __log2f(xc)) : 0.0f;
    __hip_bfloat16 h = __float2bfloat16(r);
    o.s[j] = *reinterpret_cast<ushort*>(&h);
  }
  reinterpret_cast<ushort4*>(a)[i] = o.u4;
}

// ---------------- kernel 2: WT[n][k] = bf16(w[k][n]) ------------------------
__global__ __launch_bounds__(256) void wt_kernel(const float* __restrict__ w,
                                                 __hip_bfloat16* __restrict__ wt,
                                                 int K, int N) {
  __shared__ float tile[64][65];
  const int n0 = blockIdx.x * 64;
  const int k0 = blockIdx.y * 64;
  const int tid = threadIdx.x;
#pragma unroll
  for (int i = 0; i < 16; ++i) {
    const int lin = i * 256 + tid;
    const int r = lin >> 6;   // k within tile
    const int c = lin & 63;   // n within tile
    tile[r][c] = w[(size_t)(k0 + r) * N + (n0 + c)];
  }
  __syncthreads();
  const int kk = (tid & 31) * 2;  // 0..62, even
  const int r0 = tid >> 5;        // 0..7
#pragma unroll
  for (int i = 0; i < 8; ++i) {
    const int r = r0 + i * 8;     // n within tile
    __hip_bfloat16 h0 = __float2bfloat16(tile[kk][r]);
    __hip_bfloat16 h1 = __float2bfloat16(tile[kk + 1][r]);
    ushort2 u;
    u.x = *reinterpret_cast<ushort*>(&h0);
    u.y = *reinterpret_cast<ushort*>(&h1);
    *reinterpret_cast<ushort2*>(&wt[(size_t)(n0 + r) * K + (k0 + kk)]) = u;
  }
}

// ------- kernel 3: 8-wave 128x256 GEMM, 2-phase/tile, 3-buf counted-vmcnt ---
#define BM 128
#define BN 256
#define BK 64
#define LDS_HALF 24576   // ushorts per buffer (48 KB): A[128][64] + B[256][64]
#define B_OFF 8192

#define GLD16(g, l)                                              \
  __builtin_amdgcn_global_load_lds(                              \
      (const __attribute__((address_space(1))) void*)(g),        \
      (__attribute__((address_space(3))) void*)(l), 16, 0, 0)

__global__ __launch_bounds__(512, 2) void gemm_kernel(
    const __hip_bfloat16* __restrict__ A,   // [M][K] bf16
    const __hip_bfloat16* __restrict__ BT,  // [N][K] bf16
    const float* __restrict__ bias,         // [N]
    float* __restrict__ C,                  // [M][N]
    int M, int N, int K) {
  __shared__ ushort lds[3 * LDS_HALF];   // 144 KB, 3-deep circular

  const int NTM = M / BM;               // 16
  const int NTN = N / BN;               // 16
  const int nwg = NTM * NTN;

  // XCD-aware bijective swizzle (nwg % 8 == 0 here)
  int wg = (int)blockIdx.x;
  if ((nwg & 7) == 0) wg = (wg & 7) * (nwg >> 3) + (wg >> 3);
  const int nt = wg / NTM;              // B-panel resident per XCD
  const int mt = wg % NTM;
  const int m0 = mt * BM;
  const int n0 = nt * BN;

  const int tid = threadIdx.x;
  const int lane = tid & 63;
  const int wid = tid >> 6;   // 0..7
  const int wr = wid >> 2;    // 0..1  (M half)
  const int wc = wid & 3;     // 0..3  (N quarter)

  const ushort* Au = (const ushort*)A;
  const ushort* Bu = (const ushort*)BT;

  // ---- staging (T2: pre-swizzled global source, linear LDS dest) ----
  // LDS[row][c16] holds global[row][c16 ^ (row&7)]  (c16 = 16B block in row)
  const int l8 = lane >> 3;                  // row-within-8 for every chunk
  const int c16s = (lane & 7) ^ l8;          // swizzled source col16
  const int rA0 = wid * 16 + l8;
  const int rA1 = rA0 + 8;
  const int rB0 = wid * 32 + l8;
  const ushort* aSrc0 = Au + (size_t)(m0 + rA0) * K + c16s * 8;
  const ushort* aSrc1 = Au + (size_t)(m0 + rA1) * K + c16s * 8;
  const ushort* bSrc0 = Bu + (size_t)(n0 + rB0) * K + c16s * 8;
  const ushort* bSrc1 = bSrc0 + (size_t)8 * K;
  const ushort* bSrc2 = bSrc0 + (size_t)16 * K;
  const ushort* bSrc3 = bSrc0 + (size_t)24 * K;
  const int aDst0 = wid * 1024;
  const int aDst1 = wid * 1024 + 512;
  const int bDst0 = B_OFF + wid * 2048;

  auto stageP0 = [&](ushort* ldsb, int t) {   // 3 loads: A + first B quarter
    const size_t to = (size_t)t * BK;
    GLD16(aSrc0 + to, ldsb + aDst0);
    GLD16(aSrc1 + to, ldsb + aDst1);
    GLD16(bSrc0 + to, ldsb + bDst0);
  };
  auto stageP1 = [&](ushort* ldsb, int t) {   // 3 loads: rest of B
    const size_t to = (size_t)t * BK;
    GLD16(bSrc1 + to, ldsb + bDst0 + 512);
    GLD16(bSrc2 + to, ldsb + bDst0 + 1024);
    GLD16(bSrc3 + to, ldsb + bDst0 + 1536);
  };

  // ---- fragment read addressing (swizzled ds_read) ----
  const int frow = lane & 15;
  const int lhi = lane >> 4;                 // 0..3
  const int f7 = frow & 7;
  const int aRowB = (wr * 64 + frow) * 64;           // ushort base, A region
  const int bRowB = B_OFF + (wc * 64 + frow) * 64;   // ushort base, B region

  f32x4 acc[4][4];
#pragma unroll
  for (int i = 0; i < 4; ++i)
#pragma unroll
    for (int j = 0; j < 4; ++j)
#pragma unroll
      for (int r = 0; r < 4; ++r) acc[i][j][r] = 0.0f;

  // prologue: stage tiles 0 and 1; wait only tile 0 (counted)
  stageP0(&lds[0], 0);
  stageP1(&lds[0], 0);
  stageP0(&lds[LDS_HALF], 1);
  stageP1(&lds[LDS_HALF], 1);
  asm volatile("s_waitcnt vmcnt(6)" ::: "memory");
  __builtin_amdgcn_s_barrier();

  const int NT = K / BK;
  int cur = 0;
  for (int t = 0; t < NT; ++t) {
    int nxt = cur + 2; if (nxt >= 3) nxt -= 3;
    ushort* ldsCur = &lds[cur * LDS_HALF];
    ushort* ldsNxt = &lds[nxt * LDS_HALF];
    const bool pf = (t + 2 < NT);
#pragma unroll
    for (int kk = 0; kk < 2; ++kk) {
      const int sck = ((kk * 4 + lhi) ^ f7) * 8;
      s16x8 a[4], b[4];
#pragma unroll
      for (int mi = 0; mi < 4; ++mi)
        a[mi] = *(const s16x8*)&ldsCur[aRowB + mi * 1024 + sck];
#pragma unroll
      for (int ni = 0; ni < 4; ++ni)
        b[ni] = *(const s16x8*)&ldsCur[bRowB + ni * 1024 + sck];
      // prefetch t+2 (stays in flight across barriers - counted, never drained)
      if (pf) { if (kk == 0) stageP0(ldsNxt, t + 2); else stageP1(ldsNxt, t + 2); }
      __builtin_amdgcn_s_barrier();
      __builtin_amdgcn_s_setprio(1);
#pragma unroll
      for (int mi = 0; mi < 4; ++mi)
#pragma unroll
        for (int ni = 0; ni < 4; ++ni)
          acc[mi][ni] = __builtin_amdgcn_mfma_f32_16x16x32_bf16(
              a[mi], b[ni], acc[mi][ni], 0, 0, 0);
      __builtin_amdgcn_s_setprio(0);
      if (kk == 1) {
        if (pf)              asm volatile("s_waitcnt vmcnt(6)" ::: "memory");
        else if (t + 1 < NT) asm volatile("s_waitcnt vmcnt(0)" ::: "memory");
      }
      __builtin_amdgcn_s_barrier();
    }
    cur = cur + 1; if (cur == 3) cur = 0;
  }

  // epilogue: C/D layout col = lane&15, row = (lane>>4)*4 + reg
  const int ccol = lane & 15;
  const int crow = (lane >> 4) * 4;
#pragma unroll
  for (int ni = 0; ni < 4; ++ni) {
    const int gc = n0 + wc * 64 + ni * 16 + ccol;
    const float bv = HALF_N * bias[gc];
#pragma unroll
    for (int mi = 0; mi < 4; ++mi) {
      const int gr = m0 + wr * 64 + mi * 16 + crow;
#pragma unroll
      for (int r = 0; r < 4; ++r)
        C[(size_t)(gr + r) * N + gc] = acc[mi][ni][r] + bv;
    }
  }
}

extern "C" void kernel_launch(void* const* d_in, const int* in_sizes, int n_in,
                              void* d_out, int out_size, void* d_ws, size_t ws_size,
                              hipStream_t stream) {
  const float* x = (const float*)d_in[0];
  const float* w = (const float*)d_in[1];
  const float* b = (const float*)d_in[2];
  float* y = (float*)d_out;

  const int N = in_sizes[2];             // 4096
  const int K = in_sizes[1] / N;         // 4096
  const int M = in_sizes[0] / K;         // 2048

  __hip_bfloat16* Abf = (__hip_bfloat16*)d_ws;
  __hip_bfloat16* WT  = (__hip_bfloat16*)((char*)d_ws + (size_t)M * K * 2);
  if (ws_size < (size_t)M * K * 2 + (size_t)N * K * 2) return;  // need 48 MB

  // 1) A = 3.7 * clip(x)^log2(7.4) in bf16
  const int total4 = (M * K) / 4;
  fv_kernel<<<(total4 + 255) / 256, 256, 0, stream>>>(x, Abf, total4);

  // 2) WT = transpose(w) in bf16
  wt_kernel<<<dim3(N / 64, K / 64), dim3(256), 0, stream>>>(w, WT, K, N);

  // 3) y = A @ w + 3.7*b
  const int grid = (M / BM) * (N / BN);
  gemm_kernel<<<grid, 512, 0, stream>>>(Abf, WT, b, y, M, N, K);
}